// Round 1
// baseline (675.607 us; speedup 1.0000x reference)
//
#include <hip/hip_runtime.h>

// Problem constants
#define Bn 131072
#define Dn 256
#define Hn 256
#define Cn 8

typedef __attribute__((ext_vector_type(4))) float f32x4;
typedef __attribute__((ext_vector_type(8))) __bf16 bf16x8;

#define LDA 40   // LDS row stride in bf16 units (80B): <=2-way bank aliasing = free

// ---- bf16 helpers (round-to-nearest-even) ----
__device__ inline unsigned short rtn_bf16(float v) {
    unsigned int u = __float_as_uint(v);
    unsigned int r = u + 0x7fffu + ((u >> 16) & 1u);
    return (unsigned short)(r >> 16);
}
__device__ inline float bf16_to_f(unsigned short h) {
    return __uint_as_float((unsigned int)h << 16);
}
__device__ inline void split3(float v, unsigned short& a0, unsigned short& a1,
                              unsigned short& a2) {
    a0 = rtn_bf16(v); float r = v - bf16_to_f(a0);
    a1 = rtn_bf16(r); r -= bf16_to_f(a1);
    a2 = rtn_bf16(r);
}
__device__ inline ushort4 cvt4(float4 v) {
    return make_ushort4(rtn_bf16(v.x), rtn_bf16(v.y), rtn_bf16(v.z), rtn_bf16(v.w));
}

// ---------------------------------------------------------------------------
// Prep: W1[k][n] -> 3 bf16 splits transposed [n][k] (routing-accurate path);
//       Wc1[e][k][n] -> single bf16 transposed [e][n][k] (value-accurate path).
// ---------------------------------------------------------------------------
__global__ __launch_bounds__(256)
void prep_kernel(const float* __restrict__ W1, const float* __restrict__ Wc1,
                 unsigned short* __restrict__ W1t0, unsigned short* __restrict__ W1t1,
                 unsigned short* __restrict__ W1t2, unsigned short* __restrict__ Wc1t)
{
    const int idx = blockIdx.x * 256 + threadIdx.x;
    if (idx < 65536) {
        const int n = idx >> 8, k = idx & 255;
        unsigned short a0, a1, a2;
        split3(W1[k * 256 + n], a0, a1, a2);
        W1t0[idx] = a0; W1t1[idx] = a1; W1t2[idx] = a2;
    } else {
        const int j = idx - 65536;            // 0 .. 8*65536-1
        const int e = j >> 16, rem = j & 65535;
        const int n = rem >> 8, k = rem & 255;
        Wc1t[(e << 16) + n * 256 + k] = rtn_bf16(Wc1[(e << 16) + k * 256 + n]);
    }
}

// ---------------------------------------------------------------------------
// Phase A: h = relu(x@W1+b1) via 3-split/6-product bf16 MFMA (fp32-accurate,
// needed for the tau-threshold routing); logits = h@W2+b2 fp32; routing.
// Block: 512 threads (8 waves), tile = 128 rows x 256 cols; wave w owns cols
// [w*32, w*32+32) as 2 n-tiles; 8 m-tiles of 16.
// DOUBLE-BUFFERED LDS A: stage tile i+1 (split3 VALU + ds_write) overlapped
// with MFMA on tile i; one barrier per k-step. Global x prefetch distance 2.
// ---------------------------------------------------------------------------
__global__ __launch_bounds__(512, 4)
void root_kernel(const float* __restrict__ x,
                 const unsigned short* __restrict__ Wt0,
                 const unsigned short* __restrict__ Wt1,
                 const unsigned short* __restrict__ Wt2,
                 const float* __restrict__ b1, const float* __restrict__ W2,
                 const float* __restrict__ b2, const float* __restrict__ tau,
                 float* __restrict__ out_logits, float* __restrict__ out_h,
                 float* __restrict__ out_depth, int* __restrict__ cnt,
                 int* __restrict__ lists)
{
    __shared__ unsigned short sA0[2][128 * LDA], sA1[2][128 * LDA],
                              sA2[2][128 * LDA];                          // 60 KB
    __shared__ float sP[128][8];                                          // 4 KB
    __shared__ int   sCnt[8], sBase[8], sBest[128], sSlot[128];

    const int t    = threadIdx.x;
    const int lane = t & 63;
    const int w    = t >> 6;
    const int tx   = lane & 15;
    const int q    = lane >> 4;
    const long r0  = (long)blockIdx.x * 128;

    if (t < 8) sCnt[t] = 0;
    ((float*)sP)[t] = 0.0f;
    ((float*)sP)[t + 512] = 0.0f;

    const int colA = w * 32 + tx;
    const int colB = colA + 16;
    const unsigned short* bp0 = Wt0 + colA * 256 + q * 8;
    const unsigned short* bp1 = Wt1 + colA * 256 + q * 8;
    const unsigned short* bp2 = Wt2 + colA * 256 + q * 8;
    const unsigned short* bp3 = Wt0 + colB * 256 + q * 8;
    const unsigned short* bp4 = Wt1 + colB * 256 + q * 8;
    const unsigned short* bp5 = Wt2 + colB * 256 + q * 8;

    f32x4 acc[8][2];
#pragma unroll
    for (int mt = 0; mt < 8; mt++)
#pragma unroll
        for (int nt = 0; nt < 2; nt++) acc[mt][nt] = (f32x4)0.0f;

    // staging map: thread t covers rows ar and ar+64 at float4-slot ak
    const int ar = t >> 3, ak = t & 7;
    const float4* xr0 = (const float4*)x + (r0 + ar) * 64 + ak;
    const float4* xr1 = (const float4*)x + (r0 + 64 + ar) * 64 + ak;

    auto stage = [&](int b, float4 v0, float4 v1) {
        unsigned short h0[4], h1[4], h2[4];
        split3(v0.x, h0[0], h1[0], h2[0]);
        split3(v0.y, h0[1], h1[1], h2[1]);
        split3(v0.z, h0[2], h1[2], h2[2]);
        split3(v0.w, h0[3], h1[3], h2[3]);
        *(ushort4*)&sA0[b][ar * LDA + ak * 4] = make_ushort4(h0[0], h0[1], h0[2], h0[3]);
        *(ushort4*)&sA1[b][ar * LDA + ak * 4] = make_ushort4(h1[0], h1[1], h1[2], h1[3]);
        *(ushort4*)&sA2[b][ar * LDA + ak * 4] = make_ushort4(h2[0], h2[1], h2[2], h2[3]);
        split3(v1.x, h0[0], h1[0], h2[0]);
        split3(v1.y, h0[1], h1[1], h2[1]);
        split3(v1.z, h0[2], h1[2], h2[2]);
        split3(v1.w, h0[3], h1[3], h2[3]);
        *(ushort4*)&sA0[b][(64 + ar) * LDA + ak * 4] = make_ushort4(h0[0], h0[1], h0[2], h0[3]);
        *(ushort4*)&sA1[b][(64 + ar) * LDA + ak * 4] = make_ushort4(h1[0], h1[1], h1[2], h1[3]);
        *(ushort4*)&sA2[b][(64 + ar) * LDA + ak * 4] = make_ushort4(h2[0], h2[1], h2[2], h2[3]);
    };

    // prologue: stage tile 0, hold tiles 1 and 2 pending in registers
    {
        float4 v0 = xr0[0], v1 = xr1[0];
        stage(0, v0, v1);
    }
    float4 pa0 = xr0[8],  pa1 = xr1[8];    // tile 1 pending
    float4 pb0 = xr0[16], pb1 = xr1[16];   // tile 2 pending
    __syncthreads();

    for (int i = 0; i < 8; i++) {
        const int cur = i & 1;
        const int ko  = i * 32;
        // B fragments for this k-step (L2-resident); issued before the split3
        // VALU block so their latency hides under it.
        const bf16x8 B0 = *(const bf16x8*)(bp0 + ko);
        const bf16x8 B1 = *(const bf16x8*)(bp1 + ko);
        const bf16x8 B2 = *(const bf16x8*)(bp2 + ko);
        const bf16x8 B3 = *(const bf16x8*)(bp3 + ko);
        const bf16x8 B4 = *(const bf16x8*)(bp4 + ko);
        const bf16x8 B5 = *(const bf16x8*)(bp5 + ko);

        // stage tile i+1 into the other buffer (overlaps with MFMA below)
        if (i < 7) {
            stage(cur ^ 1, pa0, pa1);
            pa0 = pb0; pa1 = pb1;
            if (i < 5) { pb0 = xr0[(i + 3) * 8]; pb1 = xr1[(i + 3) * 8]; }
        }

#pragma unroll
        for (int mt = 0; mt < 8; mt++) {
            const bf16x8 A0 = *(const bf16x8*)&sA0[cur][(mt * 16 + tx) * LDA + q * 8];
            const bf16x8 A1 = *(const bf16x8*)&sA1[cur][(mt * 16 + tx) * LDA + q * 8];
            const bf16x8 A2 = *(const bf16x8*)&sA2[cur][(mt * 16 + tx) * LDA + q * 8];
            acc[mt][0] = __builtin_amdgcn_mfma_f32_16x16x32_bf16(A0, B0, acc[mt][0], 0, 0, 0);
            acc[mt][0] = __builtin_amdgcn_mfma_f32_16x16x32_bf16(A0, B1, acc[mt][0], 0, 0, 0);
            acc[mt][0] = __builtin_amdgcn_mfma_f32_16x16x32_bf16(A1, B0, acc[mt][0], 0, 0, 0);
            acc[mt][0] = __builtin_amdgcn_mfma_f32_16x16x32_bf16(A1, B1, acc[mt][0], 0, 0, 0);
            acc[mt][0] = __builtin_amdgcn_mfma_f32_16x16x32_bf16(A0, B2, acc[mt][0], 0, 0, 0);
            acc[mt][0] = __builtin_amdgcn_mfma_f32_16x16x32_bf16(A2, B0, acc[mt][0], 0, 0, 0);
            acc[mt][1] = __builtin_amdgcn_mfma_f32_16x16x32_bf16(A0, B3, acc[mt][1], 0, 0, 0);
            acc[mt][1] = __builtin_amdgcn_mfma_f32_16x16x32_bf16(A0, B4, acc[mt][1], 0, 0, 0);
            acc[mt][1] = __builtin_amdgcn_mfma_f32_16x16x32_bf16(A1, B3, acc[mt][1], 0, 0, 0);
            acc[mt][1] = __builtin_amdgcn_mfma_f32_16x16x32_bf16(A1, B4, acc[mt][1], 0, 0, 0);
            acc[mt][1] = __builtin_amdgcn_mfma_f32_16x16x32_bf16(A0, B5, acc[mt][1], 0, 0, 0);
            acc[mt][1] = __builtin_amdgcn_mfma_f32_16x16x32_bf16(A2, B3, acc[mt][1], 0, 0, 0);
        }
        __syncthreads();
    }

    // ---- epilogue: bias+relu, store h, fp32 head partials ----
    const float b1c0 = b1[colA], b1c1 = b1[colB];
    float w20[8], w21[8];
    {
        const float4 a0 = ((const float4*)W2)[colA * 2];
        const float4 a1 = ((const float4*)W2)[colA * 2 + 1];
        const float4 c0 = ((const float4*)W2)[colB * 2];
        const float4 c1 = ((const float4*)W2)[colB * 2 + 1];
        w20[0]=a0.x; w20[1]=a0.y; w20[2]=a0.z; w20[3]=a0.w;
        w20[4]=a1.x; w20[5]=a1.y; w20[6]=a1.z; w20[7]=a1.w;
        w21[0]=c0.x; w21[1]=c0.y; w21[2]=c0.z; w21[3]=c0.w;
        w21[4]=c1.x; w21[5]=c1.y; w21[6]=c1.z; w21[7]=c1.w;
    }

#pragma unroll
    for (int mt = 0; mt < 8; mt++) {
        float pm[4][8];
#pragma unroll
        for (int reg = 0; reg < 4; reg++) {
            const float h0 = fmaxf(acc[mt][0][reg] + b1c0, 0.0f);
            const float h1 = fmaxf(acc[mt][1][reg] + b1c1, 0.0f);
            const int row = mt * 16 + q * 4 + reg;
            out_h[(r0 + row) * 256 + colA] = h0;
            out_h[(r0 + row) * 256 + colB] = h1;
#pragma unroll
            for (int c = 0; c < 8; c++)
                pm[reg][c] = h0 * w20[c] + h1 * w21[c];
        }
#pragma unroll
        for (int reg = 0; reg < 4; reg++)
#pragma unroll
            for (int c = 0; c < 8; c++) {
                float v = pm[reg][c];
                v += __shfl_xor(v, 1, 16);
                v += __shfl_xor(v, 2, 16);
                v += __shfl_xor(v, 4, 16);
                v += __shfl_xor(v, 8, 16);
                if (tx == 0) atomicAdd(&sP[mt * 16 + q * 4 + reg][c], v);
            }
    }
    __syncthreads();

    // ---- routing: one thread per row ----
    if (t < 128) {
        const long row = r0 + t;
        float l[8];
        float mx = -1e30f;
#pragma unroll
        for (int c = 0; c < 8; c++) {
            l[c] = sP[t][c] + b2[c];
            mx = fmaxf(mx, l[c]);
        }
        float e[8], s = 0.0f;
#pragma unroll
        for (int c = 0; c < 8; c++) { e[c] = expf(l[c] - mx); s += e[c]; }
        const float inv = 1.0f / s;
        int best = 0; float bp = -1.0f;
#pragma unroll
        for (int c = 0; c < 8; c++) {
            const float pr = e[c] * inv;
            const float m  = (pr >= tau[c]) ? pr : -1.0f;
            if (m > bp) { bp = m; best = c; }   // strict > == first max (jnp.argmax)
        }
        const bool routed = (bp >= 0.0f);
        float4* lo4 = (float4*)&out_logits[row * 8];
        lo4[0] = make_float4(l[0], l[1], l[2], l[3]);
        lo4[1] = make_float4(l[4], l[5], l[6], l[7]);
        out_depth[row] = routed ? 1.0f : 0.0f;
        if (routed) {
            sSlot[t] = atomicAdd(&sCnt[best], 1);
            sBest[t] = best;
        } else {
            sBest[t] = -1;
        }
    }
    __syncthreads();
    if (t < 8) sBase[t] = sCnt[t] ? atomicAdd(&cnt[t], sCnt[t]) : 0;
    __syncthreads();
    if (t < 128 && sBest[t] >= 0) {
        const int e = sBest[t];
        lists[(long)e * Bn + sBase[e] + sSlot[t]] = (int)(r0 + t);
    }
}

// ---------------------------------------------------------------------------
// Phase B: routed rows of expert e: h_c = relu(h@Wc1[e]+bc1[e]) in PLAIN bf16
// (error ~4e-3 << 8.4e-2 threshold; routing already fixed by root);
// l_c = h_c@Wc2[e]+bc2[e] fp32. Tile = 128 rows, double-buffered LDS A.
// ---------------------------------------------------------------------------
__global__ __launch_bounds__(512, 4)
void expert_kernel(const unsigned short* __restrict__ Wc1t,
                   const float* __restrict__ bc1,
                   const float* __restrict__ Wc2, const float* __restrict__ bc2,
                   float* __restrict__ out_logits, float* __restrict__ out_h,
                   const int* __restrict__ cnt, const int* __restrict__ lists)
{
    const int e = blockIdx.y;
    const int n = cnt[e];
    const int tile0 = blockIdx.x * 128;
    if (tile0 >= n) return;
    const int nrows = min(128, n - tile0);

    __shared__ unsigned short sA[2][128 * LDA];   // 20.5 KB
    __shared__ float sP[128][8];                  // 4 KB
    __shared__ int   sRidx[128];

    const int t    = threadIdx.x;
    const int lane = t & 63;
    const int w    = t >> 6;
    const int tx   = lane & 15;
    const int q    = lane >> 4;

    if (t < 128) sRidx[t] = lists[(long)e * Bn + tile0 + min(t, nrows - 1)];
    ((float*)sP)[t] = 0.0f;
    ((float*)sP)[t + 512] = 0.0f;

    const unsigned short* W = Wc1t + (long)e * 65536;
    const int colA = w * 32 + tx;
    const int colB = colA + 16;
    const unsigned short* bpA = W + colA * 256 + q * 8;
    const unsigned short* bpB = W + colB * 256 + q * 8;

    f32x4 acc[8][2];
#pragma unroll
    for (int mt = 0; mt < 8; mt++)
#pragma unroll
        for (int nt = 0; nt < 2; nt++) acc[mt][nt] = (f32x4)0.0f;

    const int ar = t >> 3, ak = t & 7;
    __syncthreads();   // sRidx visible
    const float4* hr0 = (const float4*)out_h + (long)sRidx[ar] * 64 + ak;
    const float4* hr1 = (const float4*)out_h + (long)sRidx[64 + ar] * 64 + ak;

    float4 xv0 = hr0[0], xv1 = hr1[0];
    *(ushort4*)&sA[0][ar * LDA + ak * 4]        = cvt4(xv0);
    *(ushort4*)&sA[0][(64 + ar) * LDA + ak * 4] = cvt4(xv1);
    xv0 = hr0[8]; xv1 = hr1[8];
    bf16x8 BcA = *(const bf16x8*)(bpA);
    bf16x8 BcB = *(const bf16x8*)(bpB);
    __syncthreads();

#pragma unroll 2
    for (int i = 0; i < 8; i++) {
        const int cur = i & 1;
        if (i < 7) {
            *(ushort4*)&sA[cur ^ 1][ar * LDA + ak * 4]        = cvt4(xv0);
            *(ushort4*)&sA[cur ^ 1][(64 + ar) * LDA + ak * 4] = cvt4(xv1);
            if (i < 6) { xv0 = hr0[(i + 2) * 8]; xv1 = hr1[(i + 2) * 8]; }
        }
        bf16x8 BnA, BnB;
        if (i < 7) {
            BnA = *(const bf16x8*)(bpA + (i + 1) * 32);
            BnB = *(const bf16x8*)(bpB + (i + 1) * 32);
        }
#pragma unroll
        for (int mt = 0; mt < 8; mt++) {
            const bf16x8 A = *(const bf16x8*)&sA[cur][(mt * 16 + tx) * LDA + q * 8];
            acc[mt][0] = __builtin_amdgcn_mfma_f32_16x16x32_bf16(A, BcA, acc[mt][0], 0, 0, 0);
            acc[mt][1] = __builtin_amdgcn_mfma_f32_16x16x32_bf16(A, BcB, acc[mt][1], 0, 0, 0);
        }
        if (i < 7) { BcA = BnA; BcB = BnB; }
        __syncthreads();
    }

    // ---- epilogue ----
    const float* bc1e = bc1 + (long)e * Hn;
    const float b1c0 = bc1e[colA], b1c1 = bc1e[colB];
    const float* W2c = Wc2 + (long)e * Hn * Cn;
    float w20[8], w21[8];
    {
        const float4 a0 = ((const float4*)W2c)[colA * 2];
        const float4 a1 = ((const float4*)W2c)[colA * 2 + 1];
        const float4 c0 = ((const float4*)W2c)[colB * 2];
        const float4 c1 = ((const float4*)W2c)[colB * 2 + 1];
        w20[0]=a0.x; w20[1]=a0.y; w20[2]=a0.z; w20[3]=a0.w;
        w20[4]=a1.x; w20[5]=a1.y; w20[6]=a1.z; w20[7]=a1.w;
        w21[0]=c0.x; w21[1]=c0.y; w21[2]=c0.z; w21[3]=c0.w;
        w21[4]=c1.x; w21[5]=c1.y; w21[6]=c1.z; w21[7]=c1.w;
    }

#pragma unroll
    for (int mt = 0; mt < 8; mt++) {
        float pm[4][8];
#pragma unroll
        for (int reg = 0; reg < 4; reg++) {
            const float h0 = fmaxf(acc[mt][0][reg] + b1c0, 0.0f);
            const float h1 = fmaxf(acc[mt][1][reg] + b1c1, 0.0f);
            const int row = mt * 16 + q * 4 + reg;
            if (row < nrows) {
                out_h[(long)sRidx[row] * 256 + colA] = h0;
                out_h[(long)sRidx[row] * 256 + colB] = h1;
            }
#pragma unroll
            for (int c = 0; c < 8; c++)
                pm[reg][c] = h0 * w20[c] + h1 * w21[c];
        }
#pragma unroll
        for (int reg = 0; reg < 4; reg++)
#pragma unroll
            for (int c = 0; c < 8; c++) {
                float v = pm[reg][c];
                v += __shfl_xor(v, 1, 16);
                v += __shfl_xor(v, 2, 16);
                v += __shfl_xor(v, 4, 16);
                v += __shfl_xor(v, 8, 16);
                if (tx == 0) atomicAdd(&sP[mt * 16 + q * 4 + reg][c], v);
            }
    }
    __syncthreads();

    if (t < nrows) {
        const long row = sRidx[t];
        const float* bc2e = bc2 + (long)e * Cn;
        float4* lo4 = (float4*)&out_logits[row * 8];
        lo4[0] = make_float4(sP[t][0] + bc2e[0], sP[t][1] + bc2e[1],
                             sP[t][2] + bc2e[2], sP[t][3] + bc2e[3]);
        lo4[1] = make_float4(sP[t][4] + bc2e[4], sP[t][5] + bc2e[5],
                             sP[t][6] + bc2e[6], sP[t][7] + bc2e[7]);
    }
}

extern "C" void kernel_launch(void* const* d_in, const int* in_sizes, int n_in,
                              void* d_out, int out_size, void* d_ws, size_t ws_size,
                              hipStream_t stream)
{
    const float* x   = (const float*)d_in[0];
    const float* W1  = (const float*)d_in[1];
    const float* b1  = (const float*)d_in[2];
    const float* W2  = (const float*)d_in[3];
    const float* b2  = (const float*)d_in[4];
    const float* Wc1 = (const float*)d_in[5];
    const float* bc1 = (const float*)d_in[6];
    const float* Wc2 = (const float*)d_in[7];
    const float* bc2 = (const float*)d_in[8];
    const float* tau = (const float*)d_in[9];

    float* out_logits = (float*)d_out;                       // [B, 8]
    float* out_h      = out_logits + (long)Bn * Cn;          // [B, 256]
    float* out_depth  = out_h + (long)Bn * Hn;               // [B]

    char* wsb = (char*)d_ws;
    int* cnt   = (int*)wsb;                                  // 8 counters
    int* lists = (int*)(wsb + 128);                          // 8 x B ints (4MB)
    unsigned short* W1t0 = (unsigned short*)(wsb + 128 + (size_t)8 * Bn * 4);
    unsigned short* W1t1 = W1t0 + 65536;
    unsigned short* W1t2 = W1t1 + 65536;
    unsigned short* Wc1t = W1t2 + 65536;                     // 8 x 65536 bf16

    hipMemsetAsync(d_ws, 0, 128, stream);

    prep_kernel<<<dim3((65536 + 8 * 65536) / 256), 256, 0, stream>>>(
        W1, Wc1, W1t0, W1t1, W1t2, Wc1t);

    root_kernel<<<dim3(Bn / 128), 512, 0, stream>>>(
        x, W1t0, W1t1, W1t2, b1, W2, b2, tau, out_logits, out_h, out_depth,
        cnt, lists);

    expert_kernel<<<dim3(Bn / 128, 8), 512, 0, stream>>>(
        Wc1t, bc1, Wc2, bc2, out_logits, out_h, cnt, lists);
}